// Round 1
// baseline (409.813 us; speedup 1.0000x reference)
//
#include <hip/hip_runtime.h>
#include <hip/hip_fp16.h>
#include <stdint.h>
#include <stddef.h>

#define NLVL 16
#define TABROWS 16384
#define BLK 1024
#define NBLK 1024            // 1048576 / 1024 points
#define TSCALE 8192.0f       // 2^13: keeps |emb|*scale in fp16-normal range
#define TINV   (1.0f / 8192.0f)

constexpr int RES_[NLVL]  = {16,20,25,32,40,50,64,80,101,128,161,203,256,322,406,512};
// staged bytes per level (4 B/entry fp16x2), rounded up to 16
constexpr int NBYTES_[NLVL] = {16384,32000,62512,65536,65536,65536,65536,65536,
                               65536,65536,65536,65536,65536,65536,65536,65536};

typedef __attribute__((address_space(1))) void gv_t;
typedef __attribute__((address_space(3))) void lv_t;

// ---- kernel 1: convert fp32 tables -> scaled fp16x2 in workspace (1 MiB) ----
__global__ __launch_bounds__(256) void cvt_tab(const float* __restrict__ src,
                                               uint32_t* __restrict__ dst) {
    int i = blockIdx.x * 256 + threadIdx.x;          // 131072 threads, 4 floats each
    float4 v = ((const float4*)src)[i];
    __half2 a = __floats2half2_rn(v.x * TSCALE, v.y * TSCALE);
    __half2 b = __floats2half2_rn(v.z * TSCALE, v.w * TSCALE);
    uint2 o;
    o.x = *(uint32_t*)&a;
    o.y = *(uint32_t*)&b;
    ((uint2*)dst)[i] = o;
}

// ---- kernel 2: encode. 1 point/thread, level-loop with double-buffered LDS ----
__global__ __launch_bounds__(BLK) void enc(const float* __restrict__ x,
                                           const uint32_t* __restrict__ tab,
                                           float* __restrict__ out) {
    __shared__ uint32_t lds[2][TABROWS];             // 2 x 64 KiB
    const int tid = threadIdx.x;
    const int b = blockIdx.x * BLK + tid;

    const float pc0 = x[3*b + 0];
    const float pc1 = x[3*b + 1];
    const float pc2 = x[3*b + 2];

    float acc[2 * NLVL];

    // prelude: async-stage level 0 into buffer 0
    {
        const char* g = (const char*)tab;
        char* l = (char*)&lds[0][0];
#pragma unroll
        for (int base = 0; base < NBYTES_[0]; base += BLK * 16) {
            int o = base + tid * 16;
            if (o < NBYTES_[0])
                __builtin_amdgcn_global_load_lds((gv_t*)(g + o), (lv_t*)(l + o), 16, 0, 0);
        }
    }

#pragma unroll
    for (int lvl = 0; lvl < NLVL; ++lvl) {
        // barrier: drains this wave's outstanding global_load_lds (stage of `lvl`)
        // and guarantees all waves finished gathering from the buffer we are
        // about to overwrite with the stage of `lvl+1`.
        __syncthreads();

        if (lvl + 1 < NLVL) {
            const int nb = NBYTES_[lvl + 1];
            const char* g = (const char*)tab + (size_t)(lvl + 1) * TABROWS * 4;
            char* l = (char*)&lds[(lvl + 1) & 1][0];
#pragma unroll
            for (int base = 0; base < nb; base += BLK * 16) {
                int o = base + tid * 16;
                if (o < nb)
                    __builtin_amdgcn_global_load_lds((gv_t*)(g + o), (lv_t*)(l + o), 16, 0, 0);
            }
        }

        const int r = RES_[lvl];
        const bool hashing = (lvl >= 3);
        const float rh = 0.5f * (float)r;            // exact (pow2 * small int)

        uint32_t t[3][2];
        float w[3][2];
        const float pc[3] = {pc0, pc1, pc2};
        const uint32_t PRIME[3]  = {1u, 2654435761u, 805459861u};
        const uint32_t STRIDE[3] = {1u, (uint32_t)r, (uint32_t)(r * r)};

#pragma unroll
        for (int d = 0; d < 3; ++d) {
            // ((x+1)*res)*0.5 - 0.5  ==  (x+1)*(res*0.5) - 0.5 (pow2 scaling exact)
            float xs = (pc[d] + 1.0f) * rh - 0.5f;
            float fl = floorf(xs);
            float xf = xs - fl;
            int xi = (int)fl;
            bool v0 = (xi >= 0) && (xi < r);
            bool v1 = (xi >= -1) && (xi < r - 1);
            w[d][0] = v0 ? (1.0f - xf) : 0.0f;       // validity folded into weights
            w[d][1] = v1 ? xf : 0.0f;
            if (hashing) {
                t[d][0] = (uint32_t)xi * PRIME[d];   // uint32 wrap == ref semantics
                t[d][1] = t[d][0] + PRIME[d];        // (xi+1)*P mod 2^32
            } else {
                // zeroed invalid contributions keep idx in [0, r^3) with no mod
                t[d][0] = v0 ? (uint32_t)xi * STRIDE[d] : 0u;
                t[d][1] = v1 ? (uint32_t)(xi + 1) * STRIDE[d] : 0u;
            }
        }

        const uint32_t* buf = &lds[lvl & 1][0];
        float a0 = 0.0f, a1 = 0.0f;
#pragma unroll
        for (int o0 = 0; o0 < 2; ++o0) {
#pragma unroll
            for (int o1 = 0; o1 < 2; ++o1) {
                uint32_t q01 = hashing ? (t[0][o0] ^ t[1][o1]) : (t[0][o0] + t[1][o1]);
                float w01 = w[0][o0] * w[1][o1];
#pragma unroll
                for (int o2 = 0; o2 < 2; ++o2) {
                    uint32_t idx = hashing ? ((q01 ^ t[2][o2]) & 16383u)
                                           : (q01 + t[2][o2]);
                    float wc = w01 * w[2][o2];
                    uint32_t pk = buf[idx];          // ds_read_b32: fp16x2 entry
                    __half2 h = *(__half2*)&pk;
                    a0 = fmaf(wc, __low2float(h), a0);
                    a1 = fmaf(wc, __high2float(h), a1);
                }
            }
        }
        acc[2 * lvl + 0] = a0;
        acc[2 * lvl + 1] = a1;
    }

    // epilogue: one full 128 B line per thread, 8 x float4 (undo table scale exactly)
    float4* o4 = (float4*)(out + (size_t)b * (2 * NLVL));
#pragma unroll
    for (int k = 0; k < (2 * NLVL) / 4; ++k)
        o4[k] = make_float4(acc[4*k + 0] * TINV, acc[4*k + 1] * TINV,
                            acc[4*k + 2] * TINV, acc[4*k + 3] * TINV);
}

extern "C" void kernel_launch(void* const* d_in, const int* in_sizes, int n_in,
                              void* d_out, int out_size, void* d_ws, size_t ws_size,
                              hipStream_t stream) {
    const float* x   = (const float*)d_in[0];   // (B, 3) fp32
    const float* emb = (const float*)d_in[1];   // (16, 16384, 2) fp32
    float* out = (float*)d_out;                 // (B, 16, 2) fp32
    uint32_t* tab = (uint32_t*)d_ws;            // 16*16384 fp16x2 = 1 MiB scratch

    cvt_tab<<<512, 256, 0, stream>>>(emb, tab);
    enc<<<NBLK, BLK, 0, stream>>>(x, tab, out);
}

// Round 2
// 272.649 us; speedup vs baseline: 1.5031x; 1.5031x over previous
//
#include <hip/hip_runtime.h>
#include <hip/hip_fp16.h>
#include <stdint.h>
#include <stddef.h>

#define NLVL 16
#define NLG 8               // levels per enc kernel (keeps acc in VGPRs, no spill)
#define TABROWS 16384
#define BLK 1024
#define NBLK 1024            // 1048576 / 1024 points
#define TSCALE 8192.0f       // 2^13: keeps |emb|*scale in fp16-normal range
#define TINV   (1.0f / 8192.0f)

constexpr int RES_[NLVL]  = {16,20,25,32,40,50,64,80,101,128,161,203,256,322,406,512};
// staged bytes per level (4 B/entry fp16x2), rounded up to 16
constexpr int NBYTES_[NLVL] = {16384,32000,62512,65536,65536,65536,65536,65536,
                               65536,65536,65536,65536,65536,65536,65536,65536};

typedef __attribute__((address_space(1))) void gv_t;
typedef __attribute__((address_space(3))) void lv_t;

// ---- kernel 1: convert fp32 tables -> scaled fp16x2 in workspace (1 MiB) ----
__global__ __launch_bounds__(256) void cvt_tab(const float* __restrict__ src,
                                               uint32_t* __restrict__ dst) {
    int i = blockIdx.x * 256 + threadIdx.x;          // 131072 threads, 4 floats each
    float4 v = ((const float4*)src)[i];
    __half2 a = __floats2half2_rn(v.x * TSCALE, v.y * TSCALE);
    __half2 b = __floats2half2_rn(v.z * TSCALE, v.w * TSCALE);
    uint2 o;
    o.x = *(uint32_t*)&a;
    o.y = *(uint32_t*)&b;
    ((uint2*)dst)[i] = o;
}

// ---- kernel 2: encode 8 levels [LBASE, LBASE+8). 1 point/thread,
//      double-buffered LDS, async stage of level l+1 overlaps compute of l ----
template<int LBASE>
__global__ __launch_bounds__(BLK) void enc(const float* __restrict__ x,
                                           const uint32_t* __restrict__ tab,
                                           float* __restrict__ out) {
    __shared__ uint32_t lds[2][TABROWS];             // 2 x 64 KiB
    const int tid = threadIdx.x;
    const int b = blockIdx.x * BLK + tid;

    const float pc0 = x[3*b + 0];
    const float pc1 = x[3*b + 1];
    const float pc2 = x[3*b + 2];

    float acc[2 * NLG];                              // 16 floats -> stays in VGPRs

    // prelude: async-stage level LBASE into buffer 0
    {
        const int nb = NBYTES_[LBASE];
        const char* g = (const char*)tab + (size_t)LBASE * TABROWS * 4;
        char* l = (char*)&lds[0][0];
#pragma unroll
        for (int base = 0; base < nb; base += BLK * 16) {
            int o = base + tid * 16;
            if (o < nb)
                __builtin_amdgcn_global_load_lds((gv_t*)(g + o), (lv_t*)(l + o), 16, 0, 0);
        }
    }

#pragma unroll
    for (int i = 0; i < NLG; ++i) {
        const int lvl = LBASE + i;
        // barrier: drains this wave's outstanding global_load_lds (stage of `lvl`)
        // and guarantees all waves finished gathering from the buffer we are
        // about to overwrite with the stage of `lvl+1`.
        __syncthreads();

        if (i + 1 < NLG) {
            const int nb = NBYTES_[lvl + 1];
            const char* g = (const char*)tab + (size_t)(lvl + 1) * TABROWS * 4;
            char* l = (char*)&lds[(i + 1) & 1][0];
#pragma unroll
            for (int base = 0; base < nb; base += BLK * 16) {
                int o = base + tid * 16;
                if (o < nb)
                    __builtin_amdgcn_global_load_lds((gv_t*)(g + o), (lv_t*)(l + o), 16, 0, 0);
            }
        }

        const int r = RES_[lvl];
        const bool hashing = (lvl >= 3);
        const float rh = 0.5f * (float)r;            // exact (pow2 * small int)

        uint32_t t[3][2];
        float w[3][2];
        const float pc[3] = {pc0, pc1, pc2};
        const uint32_t PRIME[3]  = {1u, 2654435761u, 805459861u};
        const uint32_t STRIDE[3] = {1u, (uint32_t)r, (uint32_t)(r * r)};

#pragma unroll
        for (int d = 0; d < 3; ++d) {
            // ((x+1)*res)*0.5 - 0.5  ==  (x+1)*(res*0.5) - 0.5 (pow2 scaling exact)
            float xs = (pc[d] + 1.0f) * rh - 0.5f;
            float fl = floorf(xs);
            float xf = xs - fl;
            int xi = (int)fl;
            bool v0 = (xi >= 0) && (xi < r);
            bool v1 = (xi >= -1) && (xi < r - 1);
            w[d][0] = v0 ? (1.0f - xf) : 0.0f;       // validity folded into weights
            w[d][1] = v1 ? xf : 0.0f;
            if (hashing) {
                t[d][0] = (uint32_t)xi * PRIME[d];   // uint32 wrap == ref semantics
                t[d][1] = t[d][0] + PRIME[d];        // (xi+1)*P mod 2^32
            } else {
                // zeroed invalid contributions keep idx in [0, r^3) with no mod
                t[d][0] = v0 ? (uint32_t)xi * STRIDE[d] : 0u;
                t[d][1] = v1 ? (uint32_t)(xi + 1) * STRIDE[d] : 0u;
            }
        }

        const uint32_t* buf = &lds[i & 1][0];
        float a0 = 0.0f, a1 = 0.0f;
#pragma unroll
        for (int o0 = 0; o0 < 2; ++o0) {
#pragma unroll
            for (int o1 = 0; o1 < 2; ++o1) {
                uint32_t q01 = hashing ? (t[0][o0] ^ t[1][o1]) : (t[0][o0] + t[1][o1]);
                float w01 = w[0][o0] * w[1][o1];
#pragma unroll
                for (int o2 = 0; o2 < 2; ++o2) {
                    uint32_t idx = hashing ? ((q01 ^ t[2][o2]) & 16383u)
                                           : (q01 + t[2][o2]);
                    float wc = w01 * w[2][o2];
                    uint32_t pk = buf[idx];          // ds_read_b32: fp16x2 entry
                    __half2 h = *(__half2*)&pk;
                    a0 = fmaf(wc, __low2float(h), a0);
                    a1 = fmaf(wc, __high2float(h), a1);
                }
            }
        }
        acc[2 * i + 0] = a0;
        acc[2 * i + 1] = a1;
    }

    // epilogue: this group's 64 B half-line, 4 x float4 (undo table scale exactly)
    float4* o4 = (float4*)(out + (size_t)b * (2 * NLVL) + 2 * LBASE);
#pragma unroll
    for (int k = 0; k < (2 * NLG) / 4; ++k)
        o4[k] = make_float4(acc[4*k + 0] * TINV, acc[4*k + 1] * TINV,
                            acc[4*k + 2] * TINV, acc[4*k + 3] * TINV);
}

extern "C" void kernel_launch(void* const* d_in, const int* in_sizes, int n_in,
                              void* d_out, int out_size, void* d_ws, size_t ws_size,
                              hipStream_t stream) {
    const float* x   = (const float*)d_in[0];   // (B, 3) fp32
    const float* emb = (const float*)d_in[1];   // (16, 16384, 2) fp32
    float* out = (float*)d_out;                 // (B, 16, 2) fp32
    uint32_t* tab = (uint32_t*)d_ws;            // 16*16384 fp16x2 = 1 MiB scratch

    cvt_tab<<<512, 256, 0, stream>>>(emb, tab);
    enc<0><<<NBLK, BLK, 0, stream>>>(x, tab, out);
    enc<8><<<NBLK, BLK, 0, stream>>>(x, tab, out);
}